// Round 2
// baseline (404.653 us; speedup 1.0000x reference)
//
#include <hip/hip_runtime.h>
#include <stdint.h>

#define AS1 __attribute__((address_space(1)))
#define AS3 __attribute__((address_space(3)))

typedef unsigned short ushort_t;
typedef __attribute__((ext_vector_type(8))) short bf16x8;
typedef __attribute__((ext_vector_type(4))) float f32x4;

__device__ __forceinline__ ushort_t f2bf(float f) {
  union { float f; uint32_t u; } c; c.f = f;
  uint32_t u = c.u;
  return (ushort_t)((u + 0x7fffu + ((u >> 16) & 1u)) >> 16);  // RNE
}

// ---------------- prep kernels ----------------

__global__ __launch_bounds__(256) void k_cvt4(const float* __restrict__ in,
                                              ushort_t* __restrict__ out, int n4) {
  int i = blockIdx.x * blockDim.x + threadIdx.x;
  int stride = gridDim.x * blockDim.x;
  for (; i < n4; i += stride) {
    float4 v = ((const float4*)in)[i];
    ushort4 o;
    o.x = f2bf(v.x); o.y = f2bf(v.y); o.z = f2bf(v.z); o.w = f2bf(v.w);
    ((ushort4*)out)[i] = o;
  }
}

__global__ __launch_bounds__(256) void k_suminit(const float* __restrict__ init,
                                                 float* __restrict__ s) {
  int i = blockIdx.x * 256 + threadIdx.x;
  if (i < 1024) s[i] = init[i] + init[i + 1024] + init[i + 2048];
}

// W [K][N] fp32 -> Wt [N][K] bf16
__global__ __launch_bounds__(256) void k_transpose(const float* __restrict__ W,
                                                   ushort_t* __restrict__ Wt,
                                                   int K, int N) {
  __shared__ float tile[32][33];
  int tx = threadIdx.x & 31, ty = threadIdx.x >> 5;  // 32 x 8
  int n0 = blockIdx.x * 32, k0 = blockIdx.y * 32;
  #pragma unroll
  for (int i = ty; i < 32; i += 8)
    tile[i][tx] = W[(size_t)(k0 + i) * N + (n0 + tx)];
  __syncthreads();
  #pragma unroll
  for (int i = ty; i < 32; i += 8)
    Wt[(size_t)(n0 + i) * K + (k0 + tx)] = f2bf(tile[tx][i]);
}

// ---------------- GEMM: C[M,1024] = A[M,KT] * Bt[1024,KT]^T  (bf16 in, fp32 acc) ----------------
// EPI 0: C = bf16(relu(acc+bias))
// EPI 1: C = bf16(3*relu(acc+bias) + extra[col])
// EPI 2: C = bf16(3*relu(acc+bias))
// EPI 3: decoder fusion: part[slot][row] = sum_cols relu(acc+bias)*extra[col]  (no C write)

template <int KT, int EPI>
__global__ __launch_bounds__(256, 2)
void gemm_bt(const ushort_t* __restrict__ A, const ushort_t* __restrict__ Bt,
             const float* __restrict__ bias, const float* __restrict__ extra,
             ushort_t* __restrict__ C, float* __restrict__ part) {
  // double-buffered LDS: buf p at smem + p*32768 (A 16KB + B 16KB per buf)
  __shared__ char smem[65536];

  // XCD-aware swizzle: nwg = 2048, divisible by 8
  const int nwg = gridDim.x;
  const int cpx = nwg >> 3;
  int bid = blockIdx.x;
  int wg = (bid & 7) * cpx + (bid >> 3);
  const int mt = wg >> 3;  // 256 m-tiles
  const int nt = wg & 7;   // 8 n-tiles

  const int t = threadIdx.x;
  const int wave = t >> 6;
  const int lane = t & 63;
  const int wr = wave >> 1, wc = wave & 1;
  const int lrow = lane & 15;
  const int kq = lane >> 4;

  const char* Abase = (const char*)A + (size_t)mt * 128 * (KT * 2);
  const char* Bbase = (const char*)Bt + (size_t)nt * 128 * (KT * 2);

  // staging geometry: call i stages rows [i*32 .. i*32+31]
  const int rbase = wave * 8 + (lane >> 3);
  // pre-swizzled global source column (16B units XORed with row&7)
  const int colOff = ((lane & 7) ^ (rbase & 7)) << 4;

  f32x4 acc[4][4];
  #pragma unroll
  for (int m = 0; m < 4; ++m)
    #pragma unroll
    for (int n = 0; n < 4; ++n)
      acc[m][n] = (f32x4){0.f, 0.f, 0.f, 0.f};

  constexpr int NKT = KT / 64;

  // prologue: stage tile 0 into buf 0 (8 loads/thread)
  {
    char* sA = smem;
    char* sB = smem + 16384;
    #pragma unroll
    for (int i = 0; i < 4; ++i) {
      int r = i * 32 + rbase;
      __builtin_amdgcn_global_load_lds(
          (const AS1 void*)(Abase + (size_t)r * (KT * 2) + colOff),
          (AS3 void*)(sA + i * 4096 + wave * 1024), 16, 0, 0);
      __builtin_amdgcn_global_load_lds(
          (const AS1 void*)(Bbase + (size_t)r * (KT * 2) + colOff),
          (AS3 void*)(sB + i * 4096 + wave * 1024), 16, 0, 0);
    }
  }

  int cur = 0;
  for (int kt = 0; kt < NKT; ++kt) {
    if (kt + 1 < NKT) {
      // issue next tile's stage into the other buffer (its old contents were
      // fully consumed before the previous iteration's end barrier)
      const size_t kb = (size_t)(kt + 1) * 128;
      char* sA = smem + (cur ^ 1) * 32768;
      char* sB = sA + 16384;
      #pragma unroll
      for (int i = 0; i < 4; ++i) {
        int r = i * 32 + rbase;
        __builtin_amdgcn_global_load_lds(
            (const AS1 void*)(Abase + (size_t)r * (KT * 2) + kb + colOff),
            (AS3 void*)(sA + i * 4096 + wave * 1024), 16, 0, 0);
        __builtin_amdgcn_global_load_lds(
            (const AS1 void*)(Bbase + (size_t)r * (KT * 2) + kb + colOff),
            (AS3 void*)(sB + i * 4096 + wave * 1024), 16, 0, 0);
      }
      // wait for tile kt's 8 loads; keep tile kt+1's 8 in flight
      asm volatile("s_waitcnt vmcnt(8)" ::: "memory");
    } else {
      asm volatile("s_waitcnt vmcnt(0)" ::: "memory");
    }
    __builtin_amdgcn_s_barrier();
    asm volatile("" ::: "memory");

    const char* smA = smem + cur * 32768;
    const char* smB = smA + 16384;
    #pragma unroll
    for (int ks = 0; ks < 2; ++ks) {
      bf16x8 af[4], bfv[4];
      #pragma unroll
      for (int m = 0; m < 4; ++m) {
        int r = wr * 64 + m * 16 + lrow;
        af[m] = *(const bf16x8*)(smA + r * 128 +
                                 ((ks * 64 + kq * 16) ^ ((r & 7) << 4)));
      }
      #pragma unroll
      for (int n = 0; n < 4; ++n) {
        int r = wc * 64 + n * 16 + lrow;
        bfv[n] = *(const bf16x8*)(smB + r * 128 +
                                  ((ks * 64 + kq * 16) ^ ((r & 7) << 4)));
      }
      #pragma unroll
      for (int m = 0; m < 4; ++m)
        #pragma unroll
        for (int n = 0; n < 4; ++n)
          acc[m][n] = __builtin_amdgcn_mfma_f32_16x16x32_bf16(af[m], bfv[n],
                                                              acc[m][n], 0, 0, 0);
    }
    asm volatile("" ::: "memory");
    __builtin_amdgcn_s_barrier();
    asm volatile("" ::: "memory");
    cur ^= 1;
  }

  // epilogue: C/D layout col = lane&15, row = (lane>>4)*4 + j
  const int row0 = mt * 128 + wr * 64;
  const int col0 = nt * 128 + wc * 64;
  if (EPI == 3) {
    float s[4][4];
    #pragma unroll
    for (int m = 0; m < 4; ++m)
      #pragma unroll
      for (int j = 0; j < 4; ++j) s[m][j] = 0.f;
    #pragma unroll
    for (int n = 0; n < 4; ++n) {
      int col = col0 + n * 16 + lrow;
      float bn = bias[col];
      float wn = extra[col];  // dec_w
      #pragma unroll
      for (int m = 0; m < 4; ++m)
        #pragma unroll
        for (int j = 0; j < 4; ++j) {
          float v = fmaxf(acc[m][n][j] + bn, 0.f);
          s[m][j] += v * wn;
        }
    }
    const int slot = nt * 2 + wc;
    #pragma unroll
    for (int m = 0; m < 4; ++m)
      #pragma unroll
      for (int j = 0; j < 4; ++j) {
        float v = s[m][j];
        v += __shfl_xor(v, 1);
        v += __shfl_xor(v, 2);
        v += __shfl_xor(v, 4);
        v += __shfl_xor(v, 8);
        if (lrow == 0)
          part[(size_t)slot * 32768 + (row0 + m * 16 + kq * 4 + j)] = v;
      }
  } else {
    #pragma unroll
    for (int n = 0; n < 4; ++n) {
      int col = col0 + n * 16 + lrow;
      float bn = bias[col];
      float en = 0.f;
      if (EPI == 1) en = extra[col];
      #pragma unroll
      for (int m = 0; m < 4; ++m) {
        int rb = row0 + m * 16 + kq * 4;
        #pragma unroll
        for (int j = 0; j < 4; ++j) {
          float v = acc[m][n][j] + bn;
          v = fmaxf(v, 0.f);
          if (EPI == 1) v = 3.f * v + en;
          else if (EPI == 2) v = 3.f * v;
          C[(size_t)(rb + j) * 1024 + col] = f2bf(v);
        }
      }
    }
  }
}

// ---------------- final decode reduce: out[r*3+{0,1,2}] = sum_s part[s][r] + dec_b ----------------

__global__ __launch_bounds__(256) void k_decfinal(const float* __restrict__ part,
                                                  const float* __restrict__ db,
                                                  float* __restrict__ out) {
  int r = blockIdx.x * 256 + threadIdx.x;
  float s = 0.f;
  #pragma unroll
  for (int i = 0; i < 16; ++i) s += part[(size_t)i * 32768 + r];
  float v = s + db[0];
  out[r * 3 + 0] = v;
  out[r * 3 + 1] = v;
  out[r * 3 + 2] = v;
}

// ---------------- launch ----------------

extern "C" void kernel_launch(void* const* d_in, const int* in_sizes, int n_in,
                              void* d_out, int out_size, void* d_ws, size_t ws_size,
                              hipStream_t stream) {
  const float* x      = (const float*)d_in[0];
  const float* enc_w1 = (const float*)d_in[1];
  const float* enc_b1 = (const float*)d_in[2];
  const float* enc_w2 = (const float*)d_in[3];
  const float* enc_b2 = (const float*)d_in[4];
  const float* initn  = (const float*)d_in[5];
  const float* g1w1   = (const float*)d_in[6];
  const float* g1b1   = (const float*)d_in[7];
  const float* g1w2   = (const float*)d_in[8];
  const float* g1b2   = (const float*)d_in[9];
  const float* g2w1   = (const float*)d_in[10];
  const float* g2b1   = (const float*)d_in[11];
  const float* g2w2   = (const float*)d_in[12];
  const float* g2b2   = (const float*)d_in[13];
  const float* dec_w  = (const float*)d_in[14];
  const float* dec_b  = (const float*)d_in[15];
  float* out = (float*)d_out;

  char* ws = (char*)d_ws;
  ushort_t* xb    = (ushort_t*)(ws + 0);          // 32768*512*2  = 33,554,432
  ushort_t* wtE1  = (ushort_t*)(ws + 33554432);   // 1024*512*2   =  1,048,576
  ushort_t* wtE2  = (ushort_t*)(ws + 34603008);   // 1024*1024*2  =  2,097,152
  ushort_t* wtG11 = (ushort_t*)(ws + 36700160);
  ushort_t* wtG12 = (ushort_t*)(ws + 38797312);
  ushort_t* wtG21 = (ushort_t*)(ws + 40894464);
  ushort_t* wtG22 = (ushort_t*)(ws + 42991616);
  float*    sInit = (float*)   (ws + 45088768);   // 4 KB
  ushort_t* bufA  = (ushort_t*)(ws + 45092864);   // 32768*1024*2 = 67,108,864
  ushort_t* bufB  = (ushort_t*)(ws + 112201728);  // 67,108,864
  float*    part  = (float*)   (ws + 112201728);  // reuse bufB region: 16*32768*4 = 2 MB

  // prep
  k_cvt4<<<2048, 256, 0, stream>>>(x, xb, 32768 * 512 / 4);
  k_suminit<<<4, 256, 0, stream>>>(initn, sInit);
  {
    dim3 g512(32, 16), g1024(32, 32);
    k_transpose<<<g512, 256, 0, stream>>>(enc_w1, wtE1, 512, 1024);
    k_transpose<<<g1024, 256, 0, stream>>>(enc_w2, wtE2, 1024, 1024);
    k_transpose<<<g1024, 256, 0, stream>>>(g1w1, wtG11, 1024, 1024);
    k_transpose<<<g1024, 256, 0, stream>>>(g1w2, wtG12, 1024, 1024);
    k_transpose<<<g1024, 256, 0, stream>>>(g2w1, wtG21, 1024, 1024);
    k_transpose<<<g1024, 256, 0, stream>>>(g2w2, wtG22, 1024, 1024);
  }

  // e1 = relu(x @ enc_w1 + b1)
  gemm_bt<512, 0><<<2048, 256, 0, stream>>>(xb, wtE1, enc_b1, nullptr, bufA, nullptr);
  // S1 = 3*relu(e1 @ enc_w2 + b2) + sum_init
  gemm_bt<1024, 1><<<2048, 256, 0, stream>>>(bufA, wtE2, enc_b2, sInit, bufB, nullptr);
  // t1 = relu(S1 @ g1w1 + g1b1)
  gemm_bt<1024, 0><<<2048, 256, 0, stream>>>(bufB, wtG11, g1b1, nullptr, bufA, nullptr);
  // m2 = 3*relu(t1 @ g1w2 + g1b2)
  gemm_bt<1024, 2><<<2048, 256, 0, stream>>>(bufA, wtG12, g1b2, nullptr, bufB, nullptr);
  // t2 = relu(m2 @ g2w1 + g2b1)
  gemm_bt<1024, 0><<<2048, 256, 0, stream>>>(bufB, wtG21, g2b1, nullptr, bufA, nullptr);
  // fused GEMM6 + decoder partials: part[slot][row] = sum_col relu(t2@g2w2+b)*dec_w
  gemm_bt<1024, 3><<<2048, 256, 0, stream>>>(bufA, wtG22, g2b2, dec_w, nullptr, part);
  // final reduce + broadcast to 3 node columns
  k_decfinal<<<128, 256, 0, stream>>>(part, dec_b, out);
}